// Round 5
// baseline (1064.429 us; speedup 1.0000x reference)
//
#include <hip/hip_runtime.h>

// PCEN: M[0]=x[0]; M[t]=(1-s)M[t-1]+s*x[t]; out=(x/(M+eps)^a + d)^r - d^r
// x, out: (64, 4000, 128) fp32.
//
// R5: single-pass decoupled-lookback scan. x is read EXACTLY once (50 regs
// per thread hold the chunk column), partial per chunk published device-wide,
// carry rebuilt from the last 10 partials (A_C^10 ~ 3e-6), emit with NT stores.
// Deadlock-free: ticket-ordered chunk assignment (a block only waits on
// strictly smaller tickets, owned by already-started blocks). Cross-XCD
// visibility via agent-scope atomics (per-XCD L2 is not coherent).
// Traffic: 131 MB rd + 128 MB NT wr + ~3 MB partials ~= HBM floor.

#define B_DIM 64
#define T_DIM 4000
#define F_DIM 128
#define NCHUNK 80
#define CLEN 50            // NCHUNK*CLEN == T_DIM
#define LOOKBACK 10        // A_C^10 ~ 3.2e-6: numerically exact
#define A_C 0.28198834f    // 0.975^50

__global__ __launch_bounds__(128) void pcen_scan(const float* __restrict__ x,
                                                 float* __restrict__ out,
                                                 int* __restrict__ ticket,
                                                 int* __restrict__ flags,
                                                 float* __restrict__ bend) {
    const float S = 0.025f, OMS = 0.975f;
    const float EPS = 1e-6f, NALPHA = -0.98f, DELTA = 2.0f, SQRTD = 1.41421356237f;

    // ---- ticket: ck-major order guarantees predecessors already started
    __shared__ int s_tk;
    if (threadIdx.x == 0) s_tk = atomicAdd(ticket, 1);
    __syncthreads();
    const int tk = s_tk;
    const int b  = tk & 63;        // B_DIM == 64
    const int ck = tk >> 6;
    const int f  = threadIdx.x;    // lane = feature -> coalesced
    const int t0 = ck * CLEN;
    const float first = (ck == 0) ? 1.0f : S;   // exact M[0]=x[0] rule

    const float* xb = x   + ((size_t)b * T_DIM + t0) * F_DIM + f;
    float*       ob = out + ((size_t)b * T_DIM + t0) * F_DIM + f;

    // ---- load chunk column into registers (50 independent coalesced loads)
    float xv[CLEN];
    #pragma unroll
    for (int s = 0; s < CLEN; ++s) xv[s] = xb[s * F_DIM];

    // ---- local zero-init scan -> chunk partial B_end
    float Bp = first * xv[0];
    #pragma unroll
    for (int s = 1; s < CLEN; ++s) Bp = __builtin_fmaf(OMS, Bp, S * xv[s]);

    // ---- publish partial (agent scope: visible across XCDs), then flag
    __hip_atomic_store(&bend[(size_t)tk * F_DIM + f], Bp,
                       __ATOMIC_RELAXED, __HIP_MEMORY_SCOPE_AGENT);
    __syncthreads();   // all 128 partial stores drained before the flag
    if (f == 0)
        __hip_atomic_store(&flags[tk], 1, __ATOMIC_RELEASE, __HIP_MEMORY_SCOPE_AGENT);

    // ---- lookback: carry = sum_{i=1..d} A_C^(i-1) * B_end[ck-i]  (Horner)
    const int d = (ck < LOOKBACK) ? ck : LOOKBACK;
    float Mc = 0.0f;
    #pragma unroll 1
    for (int j = ck - d; j < ck; ++j) {
        const int jt = (j << 6) | b;    // ticket id of (b, j)
        while (__hip_atomic_load(&flags[jt], __ATOMIC_ACQUIRE,
                                 __HIP_MEMORY_SCOPE_AGENT) == 0)
            __builtin_amdgcn_s_sleep(2);
        float Bj = __hip_atomic_load(&bend[(size_t)jt * F_DIM + f],
                                     __ATOMIC_RELAXED, __HIP_MEMORY_SCOPE_AGENT);
        Mc = __builtin_fmaf(A_C, Mc, Bj);
    }

    // ---- emit: re-scan from exact carry, fused PCEN pointwise, NT stores
    float M = Mc;                  // M_end[ck-1] (0 for ck==0)
    #pragma unroll
    for (int s = 0; s < CLEN; ++s) {
        const float ms = (s == 0) ? first : S;
        M = __builtin_fmaf(OMS, M, ms * xv[s]);
        float p = __builtin_amdgcn_exp2f(NALPHA * __builtin_amdgcn_logf(M + EPS));
        float o = __builtin_sqrtf(__builtin_fmaf(xv[s], p, DELTA)) - SQRTD;
        __builtin_nontemporal_store(o, &ob[s * F_DIM]);   // out never re-read
    }
}

extern "C" void kernel_launch(void* const* d_in, const int* in_sizes, int n_in,
                              void* d_out, int out_size, void* d_ws, size_t ws_size,
                              hipStream_t stream) {
    const float* x = (const float*)d_in[0];
    float* out = (float*)d_out;
    // ws layout: [0..4) ticket | [16..16+5120*4) flags | [32768..) partials
    int*   ticket = (int*)d_ws;
    int*   flags  = (int*)((char*)d_ws + 16);
    float* bend   = (float*)((char*)d_ws + 32768);   // 5120*128*4 = 2.62 MB
    // ws is re-poisoned 0xAA before every launch: zero ticket+flags in-graph
    hipMemsetAsync(d_ws, 0, 32768, stream);
    pcen_scan<<<B_DIM * NCHUNK, 128, 0, stream>>>(x, out, ticket, flags, bend);
}